// Round 1
// baseline (439.564 us; speedup 1.0000x reference)
//
#include <hip/hip_runtime.h>
#include <stdint.h>

#define NTAG   10
#define SEQ    512
#define BATCH  8192
#define NEG_INF -10000.0f
#define BT     (BATCH * NTAG)   // 81920, per-timestep stride in feats / bpw

// ---------------------------------------------------------------------------
// Forward Viterbi. Lane = (batch, next_tag): 10 lanes per batch element,
// 6 groups per wave (lanes 60-63 idle). fv shared across the 10-lane group
// via ds_bpermute (wave-synchronous, no barriers). Backpointers nibble-packed
// 8 steps per dword -> bpw[w*81920 + b*10 + nx], coalesced stores.
// Bitwise-exact fp32: same two adds as the reference, strict-> argmax keeps
// first max (matches jnp.argmax).
// ---------------------------------------------------------------------------
__global__ __launch_bounds__(256) void crf_fwd(
    const float* __restrict__ feats, const float* __restrict__ trans,
    float* __restrict__ path_score, int* __restrict__ last_tag,
    uint32_t* __restrict__ bpw)
{
    const int tid  = threadIdx.x;
    const int wave = tid >> 6;
    const int lane = tid & 63;
    int g  = lane / 10;            // 0..6
    const int nx = lane - g * 10;  // 0..9 (lanes 60-63: 0..3)
    const bool gvalid = (g < 6);
    if (!gvalid) g = 5;            // idle lanes mirror group 5 (never sourced)

    const int wave_b0 = blockIdx.x * 24 + wave * 6;
    if (wave_b0 >= BATCH) return;  // whole-wave early out (last block)
    const int b = wave_b0 + g;
    const bool active = gvalid && (b < BATCH);
    const int bs = (b < BATCH) ? b : (BATCH - 1);   // clamp for safe loads

    // bpermute byte indices for the 10 lanes of this group (VGPR-resident)
    int idx[NTAG];
#pragma unroll
    for (int p = 0; p < NTAG; ++p) idx[p] = (g * 10 + p) * 4;

    // this lane's transition row T[nx][p], p = prev tag
    float tr[NTAG];
#pragma unroll
    for (int p = 0; p < NTAG; ++p) tr[p] = trans[nx * NTAG + p];
    const float tstop = trans[9 * NTAG + nx];   // T[STOP][nx]

    float fv = (nx == 8) ? 0.0f : NEG_INF;      // init: START=0, else -1e4

    const float* fp = feats + bs * NTAG + nx;
    uint32_t* bp_out = bpw + bs * NTAG + nx;

    // software pipeline: 8 feats (one bp-word period) prefetched ahead
    float fc[8];
#pragma unroll
    for (int j = 0; j < 8; ++j) fc[j] = fp[j * BT];
    fp += 8 * BT;

    for (int w = 0; w < SEQ / 8; ++w) {
        float fn[8];
        if (w < SEQ / 8 - 1) {
#pragma unroll
            for (int j = 0; j < 8; ++j) fn[j] = fp[j * BT];
            fp += 8 * BT;
        } else {
#pragma unroll
            for (int j = 0; j < 8; ++j) fn[j] = 0.0f;  // dead on last iter
        }

        uint32_t bacc = 0;
#pragma unroll
        for (int j = 0; j < 8; ++j) {
            const int fvi = __float_as_int(fv);
            float best = __int_as_float(
                __builtin_amdgcn_ds_bpermute(idx[0], fvi)) + tr[0];
            int bp = 0;
#pragma unroll
            for (int p = 1; p < NTAG; ++p) {
                float v = __int_as_float(
                    __builtin_amdgcn_ds_bpermute(idx[p], fvi)) + tr[p];
                const bool gt = v > best;      // strict > : first-max wins
                bp   = gt ? p : bp;
                best = gt ? v : best;
            }
            fv = best + fc[j];                 // exact same add as reference
            bacc |= (uint32_t)bp << (4 * j);
        }
        if (active) bp_out[0] = bacc;
        bp_out += BT;
#pragma unroll
        for (int j = 0; j < 8; ++j) fc[j] = fn[j];
    }

    // terminal: term[p] = fv[p] + T[STOP][p]; max + first-argmax across group
    {
        const int ti = __float_as_int(fv + tstop);
        float best = __int_as_float(__builtin_amdgcn_ds_bpermute(idx[0], ti));
        int bt = 0;
#pragma unroll
        for (int p = 1; p < NTAG; ++p) {
            float v = __int_as_float(__builtin_amdgcn_ds_bpermute(idx[p], ti));
            const bool gt = v > best;
            bt   = gt ? p : bt;
            best = gt ? v : best;
        }
        if (active && nx == 0) { path_score[b] = best; last_tag[b] = bt; }
    }
}

// ---------------------------------------------------------------------------
// Backtrace pass A: per (chunk c, batch b, start tag0) walk the 32 steps of
// the chunk backwards, producing the chunk's composed tag map. 1.3M threads
// -> dependency chains fully latency-hidden by TLP; loads hit L1/L3 (bpw is
// 21 MB, fits Infinity Cache).
// ---------------------------------------------------------------------------
__global__ __launch_bounds__(256) void crf_chunkmap(
    const uint32_t* __restrict__ bpw, uint8_t* __restrict__ mapA)
{
    const int tid  = blockIdx.x * 256 + threadIdx.x;  // 0..1310719
    const int tag0 = tid % NTAG;
    const int rb   = tid / NTAG;                      // rb = c*8192 + b
    const int b    = rb & (BATCH - 1);
    const int c    = rb >> 13;
    int tag = tag0;
    const int tend = c * 32 + 31;
#pragma unroll
    for (int i = 0; i < 32; ++i) {
        const int t = tend - i;
        const uint32_t word = bpw[(t >> 3) * BT + b * NTAG + tag];
        tag = (word >> ((t & 7) * 4)) & 15;
    }
    mapA[rb * NTAG + tag0] = (uint8_t)tag;
}

// ---------------------------------------------------------------------------
// Backtrace pass B: resolve chunk-entry tags sequentially over the 16 chunk
// maps (tiny: 8192 threads x 15 dependent byte loads).
// ---------------------------------------------------------------------------
__global__ __launch_bounds__(256) void crf_resolve(
    const uint8_t* __restrict__ mapA, const int* __restrict__ last_tag,
    uint8_t* __restrict__ ebuf)
{
    const int b = blockIdx.x * 256 + threadIdx.x;     // 0..8191
    int tag = last_tag[b];
    ebuf[15 * BATCH + b] = (uint8_t)tag;
#pragma unroll
    for (int c = 15; c >= 1; --c) {
        tag = mapA[(c * BATCH + b) * NTAG + tag];
        ebuf[(c - 1) * BATCH + b] = (uint8_t)tag;
    }
}

// ---------------------------------------------------------------------------
// Backtrace pass C: per (chunk, batch) re-walk the chunk with the known entry
// tag, emitting best_path[t][b] (coalesced over b). Output dtype: float32.
// ---------------------------------------------------------------------------
__global__ __launch_bounds__(256) void crf_emit(
    const uint32_t* __restrict__ bpw, const uint8_t* __restrict__ ebuf,
    float* __restrict__ best_path)
{
    const int tid = blockIdx.x * 256 + threadIdx.x;   // 0..131071
    const int b = tid & (BATCH - 1);
    const int c = tid >> 13;
    int tag = ebuf[c * BATCH + b];
    const int tend = c * 32 + 31;
#pragma unroll
    for (int i = 0; i < 32; ++i) {
        const int t = tend - i;
        best_path[t * BATCH + b] = (float)tag;        // emit tag_t
        const uint32_t word = bpw[(t >> 3) * BT + b * NTAG + tag];
        tag = (word >> ((t & 7) * 4)) & 15;           // tag_{t-1}
    }
}

// ---------------------------------------------------------------------------
// d_ws layout:
//   [0, 20971520)                 bpw   : 64 words x 81920 uint32 (nibble bp)
//   [20971520, +32768)            ltag  : 8192 int32
//   [21004288, +1310720)          mapA  : 16 x 8192 x 10 bytes
//   [22315008, +131072)           ebuf  : 16 x 8192 bytes
// total ~22.4 MB
// ---------------------------------------------------------------------------
extern "C" void kernel_launch(void* const* d_in, const int* in_sizes, int n_in,
                              void* d_out, int out_size, void* d_ws, size_t ws_size,
                              hipStream_t stream)
{
    const float* feats = (const float*)d_in[0];
    const float* trans = (const float*)d_in[1];

    float* out_f      = (float*)d_out;
    float* path_score = out_f;           // [8192]
    float* best_path  = out_f + BATCH;   // [512 * 8192]

    char* ws = (char*)d_ws;
    uint32_t* bpw  = (uint32_t*)ws;
    int*      ltag = (int*)(ws + 20971520);
    uint8_t*  mapA = (uint8_t*)(ws + 20971520 + 32768);
    uint8_t*  ebuf = (uint8_t*)(ws + 20971520 + 32768 + 1310720);

    // fwd: 24 batch elems / block (4 waves x 6 groups), 342 blocks
    crf_fwd<<<342, 256, 0, stream>>>(feats, trans, path_score, ltag, bpw);
    // chunk maps: 8192 b x 16 chunks x 10 tags = 1,310,720 threads
    crf_chunkmap<<<5120, 256, 0, stream>>>(bpw, mapA);
    // resolve chunk entry tags: 8192 threads
    crf_resolve<<<32, 256, 0, stream>>>(mapA, ltag, ebuf);
    // emit: 8192 b x 16 chunks = 131,072 threads
    crf_emit<<<512, 256, 0, stream>>>(bpw, ebuf, best_path);
}

// Round 2
// 345.401 us; speedup vs baseline: 1.2726x; 1.2726x over previous
//
#include <hip/hip_runtime.h>
#include <stdint.h>

#define NTAG   10
#define SEQ    512
#define BATCH  8192
#define NEG_INF -10000.0f
#define BT     (BATCH * NTAG)   // 81920, per-timestep stride in feats / bpw
#define ROWF   12               // floats per LDS fv row (48 B: 16B-aligned)

// ---------------------------------------------------------------------------
// Forward Viterbi. Lane = (batch, next_tag): 10 lanes per batch element,
// 6 groups + 1 scratch row per wave (lanes 60-63 write to scratch row 6).
// fv shared across the 10-lane group via LDS: 1 ds_write_b32 + (b128,b128,b64)
// reads per step. Same-wave DS ops are processed in order by the LDS pipe, so
// no barrier is needed; asm memory clobbers stop compiler reordering.
// Argmax is a tournament tree (depth 4 instead of chain-9); left wins ties =
// first-max = jnp.argmax semantics. Bitwise-exact fp32 adds as the reference.
// ---------------------------------------------------------------------------
__global__ __launch_bounds__(256) void crf_fwd(
    const float* __restrict__ feats, const float* __restrict__ trans,
    float* __restrict__ path_score, int* __restrict__ last_tag,
    uint32_t* __restrict__ bpw)
{
    __shared__ float sfv[4 * 7 * ROWF];   // 4 waves x 7 rows x 12 floats

    const int tid  = threadIdx.x;
    const int wave = tid >> 6;
    const int lane = tid & 63;
    const int g    = lane / 10;           // 0..5 real, 6 = idle lanes
    const int nx   = lane - g * 10;       // 0..9 (idle lanes: 0..3)
    const bool gvalid = (g < 6);

    const int wave_b0 = blockIdx.x * 24 + wave * 6;
    if (wave_b0 >= BATCH) return;         // whole-wave early out
    const int b = wave_b0 + (gvalid ? g : 0);
    const bool active = gvalid && (b < BATCH);
    const int bs = (b < BATCH) ? b : (BATCH - 1);

    float* row = &sfv[(wave * 7 + g) * ROWF];   // g==6 -> scratch row

    // transition row T[nx][p]
    float tr[NTAG];
#pragma unroll
    for (int p = 0; p < NTAG; ++p) tr[p] = trans[nx * NTAG + p];

    float fv = (nx == 8) ? 0.0f : NEG_INF;      // START=0, else -1e4
    row[nx] = fv;
    __asm__ __volatile__("" ::: "memory");

    const float* fp = feats + bs * NTAG + nx;
    uint32_t* bp_out = bpw + bs * NTAG + nx;

    // software pipeline: 8 feats (one bp-word period) prefetched ahead
    float fc[8];
#pragma unroll
    for (int j = 0; j < 8; ++j) fc[j] = fp[j * BT];
    fp += 8 * BT;

    for (int w = 0; w < SEQ / 8; ++w) {
        float fn[8];
        if (w < SEQ / 8 - 1) {
#pragma unroll
            for (int j = 0; j < 8; ++j) fn[j] = fp[j * BT];
            fp += 8 * BT;
        } else {
#pragma unroll
            for (int j = 0; j < 8; ++j) fn[j] = 0.0f;
        }

        uint32_t bacc = 0;
#pragma unroll
        for (int j = 0; j < 8; ++j) {
            // vector LDS read of the whole fv row (b128 + b128 + b64)
            const float4 A  = *(const float4*)(row);
            const float4 Bv = *(const float4*)(row + 4);
            const float2 Cv = *(const float2*)(row + 8);
            __asm__ __volatile__("" ::: "memory");

            // candidates: exact f32 add, same as reference
            const float c0 = A.x  + tr[0];
            const float c1 = A.y  + tr[1];
            const float c2 = A.z  + tr[2];
            const float c3 = A.w  + tr[3];
            const float c4 = Bv.x + tr[4];
            const float c5 = Bv.y + tr[5];
            const float c6 = Bv.z + tr[6];
            const float c7 = Bv.w + tr[7];
            const float c8 = Cv.x + tr[8];
            const float c9 = Cv.y + tr[9];

            // tournament argmax, strict > takes right; ties keep left
            // (left subtree = smaller indices -> first-max overall)
            bool t;
            t = c1 > c0;  float v01 = t ? c1 : c0;  int i01 = t ? 1 : 0;
            t = c3 > c2;  float v23 = t ? c3 : c2;  int i23 = t ? 3 : 2;
            t = c5 > c4;  float v45 = t ? c5 : c4;  int i45 = t ? 5 : 4;
            t = c7 > c6;  float v67 = t ? c7 : c6;  int i67 = t ? 7 : 6;
            t = c9 > c8;  float v89 = t ? c9 : c8;  int i89 = t ? 9 : 8;
            t = v23 > v01; float v03 = t ? v23 : v01; int i03 = t ? i23 : i01;
            t = v67 > v45; float v47 = t ? v67 : v45; int i47 = t ? i67 : i45;
            t = v47 > v03; float v07 = t ? v47 : v03; int i07 = t ? i47 : i03;
            t = v89 > v07; float best = t ? v89 : v07; int bp = t ? i89 : i07;

            fv = best + fc[j];                  // exact same add as reference
            bacc |= (uint32_t)bp << (4 * j);

            row[nx] = fv;                       // publish for next step
            __asm__ __volatile__("" ::: "memory");
        }
        if (active) bp_out[0] = bacc;
        bp_out += BT;
#pragma unroll
        for (int j = 0; j < 8; ++j) fc[j] = fn[j];
    }

    // terminal: term[p] = fv[p] + T[STOP][p]; first-max argmax across group.
    // All lanes compute redundantly (registers only), lane nx==0 stores.
    {
        const float4 A  = *(const float4*)(row);
        const float4 Bv = *(const float4*)(row + 4);
        const float2 Cv = *(const float2*)(row + 8);

        const float c0 = A.x  + trans[90 + 0];
        const float c1 = A.y  + trans[90 + 1];
        const float c2 = A.z  + trans[90 + 2];
        const float c3 = A.w  + trans[90 + 3];
        const float c4 = Bv.x + trans[90 + 4];
        const float c5 = Bv.y + trans[90 + 5];
        const float c6 = Bv.z + trans[90 + 6];
        const float c7 = Bv.w + trans[90 + 7];
        const float c8 = Cv.x + trans[90 + 8];
        const float c9 = Cv.y + trans[90 + 9];

        bool t;
        t = c1 > c0;  float v01 = t ? c1 : c0;  int i01 = t ? 1 : 0;
        t = c3 > c2;  float v23 = t ? c3 : c2;  int i23 = t ? 3 : 2;
        t = c5 > c4;  float v45 = t ? c5 : c4;  int i45 = t ? 5 : 4;
        t = c7 > c6;  float v67 = t ? c7 : c6;  int i67 = t ? 7 : 6;
        t = c9 > c8;  float v89 = t ? c9 : c8;  int i89 = t ? 9 : 8;
        t = v23 > v01; float v03 = t ? v23 : v01; int i03 = t ? i23 : i01;
        t = v67 > v45; float v47 = t ? v67 : v45; int i47 = t ? i67 : i45;
        t = v47 > v03; float v07 = t ? v47 : v03; int i07 = t ? i47 : i03;
        t = v89 > v07; float best = t ? v89 : v07; int bt = t ? i89 : i07;

        if (active && nx == 0) { path_score[b] = best; last_tag[b] = bt; }
    }
}

// ---------------------------------------------------------------------------
// Backtrace pass A: per (chunk c, batch b, start tag0) walk the 32 steps of
// the chunk backwards, producing the chunk's composed tag map.
// ---------------------------------------------------------------------------
__global__ __launch_bounds__(256) void crf_chunkmap(
    const uint32_t* __restrict__ bpw, uint8_t* __restrict__ mapA)
{
    const int tid  = blockIdx.x * 256 + threadIdx.x;  // 0..1310719
    const int tag0 = tid % NTAG;
    const int rb   = tid / NTAG;                      // rb = c*8192 + b
    const int b    = rb & (BATCH - 1);
    const int c    = rb >> 13;
    int tag = tag0;
    const int tend = c * 32 + 31;
#pragma unroll
    for (int i = 0; i < 32; ++i) {
        const int t = tend - i;
        const uint32_t word = bpw[(t >> 3) * BT + b * NTAG + tag];
        tag = (word >> ((t & 7) * 4)) & 15;
    }
    mapA[rb * NTAG + tag0] = (uint8_t)tag;
}

// ---------------------------------------------------------------------------
// Backtrace pass B: resolve chunk-entry tags sequentially over 16 chunk maps.
// ---------------------------------------------------------------------------
__global__ __launch_bounds__(256) void crf_resolve(
    const uint8_t* __restrict__ mapA, const int* __restrict__ last_tag,
    uint8_t* __restrict__ ebuf)
{
    const int b = blockIdx.x * 256 + threadIdx.x;     // 0..8191
    int tag = last_tag[b];
    ebuf[15 * BATCH + b] = (uint8_t)tag;
#pragma unroll
    for (int c = 15; c >= 1; --c) {
        tag = mapA[(c * BATCH + b) * NTAG + tag];
        ebuf[(c - 1) * BATCH + b] = (uint8_t)tag;
    }
}

// ---------------------------------------------------------------------------
// Backtrace pass C: re-walk each chunk with known entry tag, emit best_path.
// ---------------------------------------------------------------------------
__global__ __launch_bounds__(256) void crf_emit(
    const uint32_t* __restrict__ bpw, const uint8_t* __restrict__ ebuf,
    float* __restrict__ best_path)
{
    const int tid = blockIdx.x * 256 + threadIdx.x;   // 0..131071
    const int b = tid & (BATCH - 1);
    const int c = tid >> 13;
    int tag = ebuf[c * BATCH + b];
    const int tend = c * 32 + 31;
#pragma unroll
    for (int i = 0; i < 32; ++i) {
        const int t = tend - i;
        best_path[t * BATCH + b] = (float)tag;        // emit tag_t
        const uint32_t word = bpw[(t >> 3) * BT + b * NTAG + tag];
        tag = (word >> ((t & 7) * 4)) & 15;           // tag_{t-1}
    }
}

// ---------------------------------------------------------------------------
// d_ws layout:
//   [0, 20971520)                 bpw   : 64 words x 81920 uint32 (nibble bp)
//   [20971520, +32768)            ltag  : 8192 int32
//   [21004288, +1310720)          mapA  : 16 x 8192 x 10 bytes
//   [22315008, +131072)           ebuf  : 16 x 8192 bytes
// ---------------------------------------------------------------------------
extern "C" void kernel_launch(void* const* d_in, const int* in_sizes, int n_in,
                              void* d_out, int out_size, void* d_ws, size_t ws_size,
                              hipStream_t stream)
{
    const float* feats = (const float*)d_in[0];
    const float* trans = (const float*)d_in[1];

    float* out_f      = (float*)d_out;
    float* path_score = out_f;           // [8192]
    float* best_path  = out_f + BATCH;   // [512 * 8192]

    char* ws = (char*)d_ws;
    uint32_t* bpw  = (uint32_t*)ws;
    int*      ltag = (int*)(ws + 20971520);
    uint8_t*  mapA = (uint8_t*)(ws + 20971520 + 32768);
    uint8_t*  ebuf = (uint8_t*)(ws + 20971520 + 32768 + 1310720);

    crf_fwd<<<342, 256, 0, stream>>>(feats, trans, path_score, ltag, bpw);
    crf_chunkmap<<<5120, 256, 0, stream>>>(bpw, mapA);
    crf_resolve<<<32, 256, 0, stream>>>(mapA, ltag, ebuf);
    crf_emit<<<512, 256, 0, stream>>>(bpw, ebuf, best_path);
}